// Round 6
// baseline (1167.098 us; speedup 1.0000x reference)
//
#include <hip/hip_runtime.h>
#include <cmath>

#define BATCH 64
#define SEQL  32
#define EMBD  300
#define HIDD  500
#define NOBJ  64
#define GHID  100
#define ANSN  1000
#define MCOL  2048   // t*64+b column dimension
#define LBLK  250    // LSTM blocks (2 units each)
#define SLOTP 32     // slot padding in ints (128 B)

__device__ __forceinline__ float sigmf(float x){ return 1.f/(1.f+expf(-x)); }

// coherent (sc1, L2-bypass) primitives: RELAXED agent-scope atomics -> no cache-wide fences
__device__ __forceinline__ void st_cc(float* p, float v){
    __hip_atomic_store(p, v, __ATOMIC_RELAXED, __HIP_MEMORY_SCOPE_AGENT);
}
__device__ __forceinline__ float2 ld_cc2(const unsigned long long* p){
    union { unsigned long long u; float2 f; } c;
    c.u = __hip_atomic_load(p, __ATOMIC_RELAXED, __HIP_MEMORY_SCOPE_AGENT);
    return c.f;
}

// ---------------- embT[k][t*64+b] = table[sent[b*32+t]][k] ----------------
__global__ void k_embT(const int* __restrict__ sent, const float* __restrict__ table,
                       float* __restrict__ embT)
{
    __shared__ float T[64][101];
    int t  = blockIdx.y;
    int k0 = blockIdx.x * 100;
    int tid = threadIdx.x;
    for (int i = tid; i < 64*100; i += 256){
        int b = i / 100, k = i - b*100;
        T[b][k] = table[(size_t)sent[b*SEQL + t]*EMBD + k0 + k];
    }
    __syncthreads();
    for (int i = tid; i < 100*64; i += 256){
        int k = i >> 6, b = i & 63;
        embT[(size_t)(k0+k)*MCOL + t*64 + b] = T[b][k];
    }
}

// ---------------- NN GEMM: C[n][m] = sum_k A[n][k]*B[k][m] + bias0[n]+bias1[n] ----------------
__global__ __launch_bounds__(256) void k_gemm_nn(const float* __restrict__ A, const float* __restrict__ B,
                 const float* __restrict__ bias0, const float* __restrict__ bias1,
                 float* __restrict__ C, int N, int M, int K)
{
    __shared__ float As[16][65];
    __shared__ float Bs[16][65];
    int n0 = blockIdx.y*64, m0 = blockIdx.x*64;
    int tid = threadIdx.x, tx = tid & 15, ty = tid >> 4;
    float acc[4][4] = {};
    for (int k0 = 0; k0 < K; k0 += 16){
        for (int i = tid; i < 64*16; i += 256){
            int n = i >> 4, k = i & 15;
            As[k][n] = (n0+n < N && k0+k < K) ? A[(size_t)(n0+n)*K + k0+k] : 0.f;
        }
        for (int i = tid; i < 16*64; i += 256){
            int k = i >> 6, m = i & 63;
            Bs[k][m] = (k0+k < K) ? B[(size_t)(k0+k)*M + m0+m] : 0.f;
        }
        __syncthreads();
        #pragma unroll
        for (int kk = 0; kk < 16; ++kk){
            float a[4], b[4];
            #pragma unroll
            for (int i=0;i<4;i++) a[i] = As[kk][ty*4+i];
            #pragma unroll
            for (int j=0;j<4;j++) b[j] = Bs[kk][tx*4+j];
            #pragma unroll
            for (int i=0;i<4;i++)
                #pragma unroll
                for (int j=0;j<4;j++) acc[i][j] += a[i]*b[j];
        }
        __syncthreads();
    }
    #pragma unroll
    for (int i=0;i<4;i++){
        int n = n0 + ty*4 + i;
        if (n >= N) continue;
        float bsum = bias0[n] + bias1[n];
        float4 v;
        v.x = acc[i][0]+bsum; v.y = acc[i][1]+bsum; v.z = acc[i][2]+bsum; v.w = acc[i][3]+bsum;
        *(float4*)(C + (size_t)n*M + m0 + tx*4) = v;
    }
}

// ---------------- distributed barrier, fence-free (RELAXED sc1 atomics only) ----------------
// Producer ordering: the entry __syncthreads drains vmcnt(0) per wave, so all prior sc1
// h-stores are acked at the coherence point before tid0's slot store issues.
__device__ __forceinline__ void gbar2(int* slots, int* go, int seq)
{
    __syncthreads();
    if (blockIdx.x == 0){
        if (threadIdx.x < LBLK-1){
            int* s = slots + threadIdx.x*SLOTP;
            while (__hip_atomic_load(s, __ATOMIC_RELAXED, __HIP_MEMORY_SCOPE_AGENT) < seq)
                __builtin_amdgcn_s_sleep(1);
        }
        __syncthreads();
        if (threadIdx.x == 0)
            __hip_atomic_store(go, seq, __ATOMIC_RELAXED, __HIP_MEMORY_SCOPE_AGENT);
    } else {
        if (threadIdx.x == 0){
            __hip_atomic_store(slots + (blockIdx.x-1)*SLOTP, seq,
                               __ATOMIC_RELAXED, __HIP_MEMORY_SCOPE_AGENT);
            while (__hip_atomic_load(go, __ATOMIC_RELAXED, __HIP_MEMORY_SCOPE_AGENT) < seq)
                __builtin_amdgcn_s_sleep(1);
        }
    }
    asm volatile("" ::: "memory");
    __syncthreads();
}

// ---------------- LSTM v6: fence-free h exchange; W_hh stays L2/K$-resident ----------------
// hW layout: [buf][k 0..511][b 0..63]; step t reads buf (t&1)^1, writes buf t&1; h(-1) in buf1.
// All hW accesses inside this kernel are sc1 (coherence-point); W_hh/xgT stay plain cached.
__global__ __launch_bounds__(256, 1) void k_lstm_v6(float* __restrict__ hW,
    const float* __restrict__ xgT, const float* __restrict__ Whh,
    const float* __restrict__ h0, const float* __restrict__ c0,
    const int* __restrict__ lens, int* __restrict__ slots, int* __restrict__ go)
{
    __shared__ float hs[4][8192];   // 128 KB: [wave][k_local*64 + b]
    __shared__ float gl[2048];      // 8 KB: [wave*8 + r][b] partial gates

    int tid  = threadIdx.x;
    int bid  = blockIdx.x;
    int u0   = bid * 2;
    int w    = __builtin_amdgcn_readfirstlane(tid >> 6);
    int lane = tid & 63;

    // persistent pointwise state (threads 0..127): uu = tid>>6, b = lane
    float cprev = 0.f, hprev = 0.f; int mylen = 0;
    if (tid < 128){
        int b = lane, uu = tid >> 6;
        cprev = c0[b*HIDD + u0 + uu];
        hprev = h0[b*HIDD + u0 + uu];
        mylen = lens[b];
        st_cc(&hW[(size_t)(1*512 + u0 + uu)*64 + b], hprev);   // h(-1) -> buf1
    }
    if (bid == 0){                   // zero pad rows 500..511, both buffers
        for (int i = tid; i < 2*12*64; i += 256){
            int buf = i / 768, rem = i - buf*768;
            st_cc(&hW[(size_t)(buf*512 + 500 + (rem >> 6))*64 + (rem & 63)], 0.f);
        }
    }
    gbar2(slots, go, 1);             // init barrier

    const int kq0 = w * 128;

    for (int t = 0; t < SEQL; ++t){
        // stage this wave's k-quarter of h(t-1) into hs[w] (wave-private region, no block sync)
        {
            const unsigned long long* src =
                (const unsigned long long*)(hW + (size_t)((((t&1)^1)*512) + kq0)*64);
            float2* dst = (float2*)(&hs[w][0]);
            #pragma unroll 16
            for (int i = 0; i < 64; ++i)
                dst[i*64 + lane] = ld_cc2(src + i*64 + lane);
        }
        float acc[8] = {0,0,0,0,0,0,0,0};
        #pragma unroll 4
        for (int k4 = 0; k4 < 128; k4 += 4){
            int kk = kq0 + k4;
            if (kk < HIDD){                      // wave-uniform tail guard
                float a0 = hs[w][(k4+0)*64 + lane];
                float a1 = hs[w][(k4+1)*64 + lane];
                float a2 = hs[w][(k4+2)*64 + lane];
                float a3 = hs[w][(k4+3)*64 + lane];
                #pragma unroll
                for (int r = 0; r < 8; ++r){
                    int row = (r>>1)*HIDD + u0 + (r&1);   // gate g=r>>1, unit uu=r&1
                    float4 wv = *(const float4*)(Whh + (size_t)row*HIDD + kk);  // uniform -> s_load
                    acc[r] += a0*wv.x + a1*wv.y + a2*wv.z + a3*wv.w;
                }
            }
        }
        #pragma unroll
        for (int r = 0; r < 8; ++r) gl[(w*8 + r)*64 + lane] = acc[r];
        __syncthreads();
        if (tid < 128){
            int b = lane, uu = tid >> 6;
            float g4[4];
            #pragma unroll
            for (int g = 0; g < 4; ++g){
                int r = g*2 + uu;
                float s = gl[r*64+b] + gl[(8+r)*64+b] + gl[(16+r)*64+b] + gl[(24+r)*64+b];
                s += xgT[(size_t)(g*HIDD + u0 + uu)*MCOL + t*64 + b];
                g4[g] = s;
            }
            float si = sigmf(g4[0]);
            float sf = sigmf(g4[1]);
            float tg = tanhf(g4[2]);
            float so = sigmf(g4[3]);
            float cn = sf*cprev + si*tg;
            float hn = so*tanhf(cn);
            if (t < mylen){ cprev = cn; hprev = hn; }
            st_cc(&hW[(size_t)((t&1)*512 + u0 + uu)*64 + b], hprev);
        }
        if (t < SEQL-1) gbar2(slots, go, t + 2);   // last step: kernel-end is the fence
    }
}

// ---------------- q_part: qp[b][n] = sum_k h31[k][b]*g1w[n][k] + g1b[n] ----------------
__global__ void k_qp(const float* __restrict__ hq, const float* __restrict__ g1w,
                     const float* __restrict__ g1b, float* __restrict__ qp)
{
    int idx = blockIdx.x*blockDim.x + threadIdx.x;
    if (idx >= BATCH*GHID) return;
    int b = idx / GHID, n = idx % GHID;
    const float* wr = g1w + n*548;
    float s = g1b[n];
    for (int k = 0; k < HIDD; ++k) s += hq[k*64 + b]*wr[k];
    qp[idx] = s;
}

// ---------------- i_part/j_part ----------------
__global__ void k_ipjp(const float* __restrict__ conv, const float* __restrict__ g1w,
                       float* __restrict__ ip, float* __restrict__ jp)
{
    int idx = blockIdx.x*blockDim.x + threadIdx.x;
    if (idx >= BATCH*NOBJ*GHID) return;
    int b = idx / (NOBJ*GHID);
    int rem = idx - b*(NOBJ*GHID);
    int o = rem / GHID, n = rem % GHID;
    const float* wj = g1w + n*548 + 500;
    const float* wi = g1w + n*548 + 524;
    float si = 0.f, sj = 0.f;
    #pragma unroll
    for (int c = 0; c < 24; ++c){
        float v = conv[((size_t)b*24 + c)*NOBJ + o];
        sj += v*wj[c];
        si += v*wi[c];
    }
    ip[idx] = si;
    jp[idx] = sj;
}

// ---------------- fused pair kernel: 2 i's x 64 j's per block ----------------
__global__ __launch_bounds__(256, 2) void k_pair(const float* __restrict__ qp, const float* __restrict__ ip,
              const float* __restrict__ jp, const float* __restrict__ g2w,
              const float* __restrict__ g2b, float* __restrict__ part)
{
    __shared__ float jpl[NOBJ][GHID+1];
    __shared__ float basel[2][GHID];
    __shared__ float g2wl[GHID*GHID];
    int b  = blockIdx.x >> 5;
    int ic = blockIdx.x & 31;
    int tid = threadIdx.x;
    for (int i = tid; i < NOBJ*GHID; i += 256){
        int j = i / GHID, k = i % GHID;
        jpl[j][k] = jp[((size_t)b*NOBJ + j)*GHID + k];
    }
    for (int i = tid; i < 2*GHID; i += 256){
        int ii = i / GHID, k = i % GHID;
        basel[ii][k] = qp[b*GHID + k] + ip[((size_t)b*NOBJ + ic*2 + ii)*GHID + k];
    }
    for (int i = tid; i < GHID*GHID; i += 256) g2wl[i] = g2w[i];
    __syncthreads();

    int j  = tid & 63;
    int nt = tid >> 6;
    float acc[2][25] = {};
    for (int k = 0; k < GHID; ++k){
        float jv = jpl[j][k];
        float a0 = fmaxf(basel[0][k] + jv, 0.f);
        float a1 = fmaxf(basel[1][k] + jv, 0.f);
        #pragma unroll
        for (int nn = 0; nn < 25; ++nn){
            float w = g2wl[(nt*25+nn)*GHID + k];
            acc[0][nn] += a0*w;
            acc[1][nn] += a1*w;
        }
    }
    #pragma unroll
    for (int nn = 0; nn < 25; ++nn){
        int n = nt*25 + nn;
        float gb = g2b[n];
        float s = fmaxf(acc[0][nn]+gb, 0.f) + fmaxf(acc[1][nn]+gb, 0.f);
        #pragma unroll
        for (int off = 32; off > 0; off >>= 1) s += __shfl_down(s, off);
        if ((tid & 63) == 0) part[(size_t)blockIdx.x*GHID + n] = s;
    }
}

// ---------------- final: reduce partials, f1, f2, log_softmax ----------------
__global__ __launch_bounds__(256) void k_final(const float* __restrict__ part, const float* __restrict__ f1w,
               const float* __restrict__ f1b, const float* __restrict__ f2w,
               const float* __restrict__ f2b, float* __restrict__ out)
{
    int b = blockIdx.x;
    int tid = threadIdx.x;
    __shared__ float gs[GHID];
    __shared__ float fh[GHID];
    __shared__ float lg[ANSN];
    __shared__ float red[4], red2[4];
    if (tid < GHID){
        float s = 0.f;
        for (int ic = 0; ic < 32; ++ic) s += part[((size_t)b*32 + ic)*GHID + tid];
        gs[tid] = s;
    }
    __syncthreads();
    if (tid < GHID){
        float s = f1b[tid];
        const float* w = f1w + tid*GHID;
        for (int k = 0; k < GHID; ++k) s += gs[k]*w[k];
        fh[tid] = fmaxf(s, 0.f);
    }
    __syncthreads();
    for (int n = tid; n < ANSN; n += 256){
        float s = f2b[n];
        const float* w = f2w + (size_t)n*GHID;
        for (int k = 0; k < GHID; ++k) s += fh[k]*w[k];
        lg[n] = fmaxf(s, 0.f);
    }
    __syncthreads();
    float mx = -1e30f;
    for (int n = tid; n < ANSN; n += 256) mx = fmaxf(mx, lg[n]);
    #pragma unroll
    for (int off = 32; off > 0; off >>= 1) mx = fmaxf(mx, __shfl_xor(mx, off));
    if ((tid & 63) == 0) red[tid >> 6] = mx;
    __syncthreads();
    mx = fmaxf(fmaxf(red[0], red[1]), fmaxf(red[2], red[3]));
    float se = 0.f;
    for (int n = tid; n < ANSN; n += 256) se += expf(lg[n]-mx);
    #pragma unroll
    for (int off = 32; off > 0; off >>= 1) se += __shfl_xor(se, off);
    if ((tid & 63) == 0) red2[tid >> 6] = se;
    __syncthreads();
    se = red2[0]+red2[1]+red2[2]+red2[3];
    float lse = logf(se);
    for (int n = tid; n < ANSN; n += 256) out[(size_t)b*ANSN + n] = lg[n] - mx - lse;
}

extern "C" void kernel_launch(void* const* d_in, const int* in_sizes, int n_in,
                              void* d_out, int out_size, void* d_ws, size_t ws_size,
                              hipStream_t stream)
{
    const int*   sent  = (const int*)  d_in[0];
    const float* conv  = (const float*)d_in[1];
    const int*   lens  = (const int*)  d_in[2];
    const float* table = (const float*)d_in[3];
    const float* W_ih  = (const float*)d_in[4];
    const float* W_hh  = (const float*)d_in[5];
    const float* b_ih  = (const float*)d_in[6];
    const float* b_hh  = (const float*)d_in[7];
    const float* h0    = (const float*)d_in[8];
    const float* c0    = (const float*)d_in[9];
    const float* g1_w  = (const float*)d_in[10];
    const float* g1_b  = (const float*)d_in[11];
    const float* g2_w  = (const float*)d_in[12];
    const float* g2_b  = (const float*)d_in[13];
    const float* f1_w  = (const float*)d_in[14];
    const float* f1_b  = (const float*)d_in[15];
    const float* f2_w  = (const float*)d_in[16];
    const float* f2_b  = (const float*)d_in[17];
    float* out = (float*)d_out;

    float* ws   = (float*)d_ws;
    int*   go   = (int*)d_ws;                          // 1 word (own line)
    int*   slots= (int*)d_ws + SLOTP;                  // 249 slots * 32 ints
    float* hW   = ws + 16384;                          // 2*512*64 = 65536  (64 KB barrier region)
    float* embT = hW + 2*512*64;                       // 300*2048
    float* xgT  = embT + (size_t)EMBD*MCOL;            // 2000*2048
    float* qp   = xgT  + (size_t)4*HIDD*MCOL;          // 64*100
    float* ip   = qp   + BATCH*GHID;                   // 64*64*100
    float* jp   = ip   + BATCH*NOBJ*GHID;
    float* part = jp   + BATCH*NOBJ*GHID;              // 2048*100

    // 0. zero barrier region (every launch -> deterministic across graph replays)
    hipMemsetAsync(go, 0, 16384*sizeof(float), stream);

    // 1. embedding gather, transposed
    {
        dim3 g(3, SEQL);
        k_embT<<<g, 256, 0, stream>>>(sent, table, embT);
    }

    // 2. xgT = W_ih @ embT + (b_ih+b_hh)
    {
        dim3 g(MCOL/64, (4*HIDD + 63)/64);
        k_gemm_nn<<<g, 256, 0, stream>>>(W_ih, embT, b_ih, b_hh, xgT,
                                         4*HIDD, MCOL, EMBD);
    }

    // 3. LSTM, 250 blocks, fence-free distributed barrier (cooperative launch for residency)
    {
        float* hW_p = hW; const float* xgT_p = xgT;
        const float* Whh_p = W_hh; const float* h0_p = h0;
        const float* c0_p = c0; const int* lens_p = lens;
        int* slots_p = slots; int* go_p = go;
        void* kargs[] = { (void*)&hW_p, (void*)&xgT_p, (void*)&Whh_p,
                          (void*)&h0_p, (void*)&c0_p, (void*)&lens_p,
                          (void*)&slots_p, (void*)&go_p };
        hipLaunchCooperativeKernel((const void*)k_lstm_v6, dim3(LBLK), dim3(256),
                                   kargs, 0, stream);
    }
    const float* hq = hW + (size_t)512*64;   // buf1 holds h(31)

    // 4. g_mlp layer-1 partials
    k_qp<<<(BATCH*GHID + 255)/256, 256, 0, stream>>>(hq, g1_w, g1_b, qp);
    k_ipjp<<<(BATCH*NOBJ*GHID + 255)/256, 256, 0, stream>>>(conv, g1_w, ip, jp);

    // 5. fused pair kernel (2 i's per block) -> partial sums
    k_pair<<<BATCH*32, 256, 0, stream>>>(qp, ip, jp, g2_w, g2_b, part);

    // 6. final MLP + log_softmax
    k_final<<<BATCH, 256, 0, stream>>>(part, f1_w, f1_b, f2_w, f2_b, out);
}

// Round 7
// 604.283 us; speedup vs baseline: 1.9314x; 1.9314x over previous
//
#include <hip/hip_runtime.h>
#include <cmath>

#define BATCH 64
#define SEQL  32
#define EMBD  300
#define HIDD  500
#define NOBJ  64
#define GHID  100
#define ANSN  1000
#define MCOL  2048   // t*64+b column dimension
#define VBLK  125    // LSTM blocks (4 units each)
#define SLOTP 32     // slot padding in ints (128 B)

typedef _Float16 half8 __attribute__((ext_vector_type(8)));
typedef float    f32x4 __attribute__((ext_vector_type(4)));

__device__ __forceinline__ float sigmf(float x){ return 1.f/(1.f+expf(-x)); }

// ---------------- embT[k][t*64+b] = table[sent[b*32+t]][k] ----------------
__global__ void k_embT(const int* __restrict__ sent, const float* __restrict__ table,
                       float* __restrict__ embT)
{
    __shared__ float T[64][101];
    int t  = blockIdx.y;
    int k0 = blockIdx.x * 100;
    int tid = threadIdx.x;
    for (int i = tid; i < 64*100; i += 256){
        int b = i / 100, k = i - b*100;
        T[b][k] = table[(size_t)sent[b*SEQL + t]*EMBD + k0 + k];
    }
    __syncthreads();
    for (int i = tid; i < 100*64; i += 256){
        int k = i >> 6, b = i & 63;
        embT[(size_t)(k0+k)*MCOL + t*64 + b] = T[b][k];
    }
}

// ---------------- NN GEMM: C[n][m] = sum_k A[n][k]*B[k][m] + bias0[n]+bias1[n] ----------------
__global__ __launch_bounds__(256) void k_gemm_nn(const float* __restrict__ A, const float* __restrict__ B,
                 const float* __restrict__ bias0, const float* __restrict__ bias1,
                 float* __restrict__ C, int N, int M, int K)
{
    __shared__ float As[16][65];
    __shared__ float Bs[16][65];
    int n0 = blockIdx.y*64, m0 = blockIdx.x*64;
    int tid = threadIdx.x, tx = tid & 15, ty = tid >> 4;
    float acc[4][4] = {};
    for (int k0 = 0; k0 < K; k0 += 16){
        for (int i = tid; i < 64*16; i += 256){
            int n = i >> 4, k = i & 15;
            As[k][n] = (n0+n < N && k0+k < K) ? A[(size_t)(n0+n)*K + k0+k] : 0.f;
        }
        for (int i = tid; i < 16*64; i += 256){
            int k = i >> 6, m = i & 63;
            Bs[k][m] = (k0+k < K) ? B[(size_t)(k0+k)*M + m0+m] : 0.f;
        }
        __syncthreads();
        #pragma unroll
        for (int kk = 0; kk < 16; ++kk){
            float a[4], b[4];
            #pragma unroll
            for (int i=0;i<4;i++) a[i] = As[kk][ty*4+i];
            #pragma unroll
            for (int j=0;j<4;j++) b[j] = Bs[kk][tx*4+j];
            #pragma unroll
            for (int i=0;i<4;i++)
                #pragma unroll
                for (int j=0;j<4;j++) acc[i][j] += a[i]*b[j];
        }
        __syncthreads();
    }
    #pragma unroll
    for (int i=0;i<4;i++){
        int n = n0 + ty*4 + i;
        if (n >= N) continue;
        float bsum = bias0[n] + bias1[n];
        float4 v;
        v.x = acc[i][0]+bsum; v.y = acc[i][1]+bsum; v.z = acc[i][2]+bsum; v.w = acc[i][3]+bsum;
        *(float4*)(C + (size_t)n*M + m0 + tx*4) = v;
    }
}

// ---------------- distributed barrier (r5-proven): slots + block-0 aggregator ----------------
__device__ __forceinline__ void gbar2(int* slots, int* go, int seq)
{
    __syncthreads();
    if (blockIdx.x == 0){
        if (threadIdx.x < VBLK-1){
            int* s = slots + threadIdx.x*SLOTP;
            while (__hip_atomic_load(s, __ATOMIC_RELAXED, __HIP_MEMORY_SCOPE_AGENT) < seq)
                __builtin_amdgcn_s_sleep(1);
            (void)__hip_atomic_load(s, __ATOMIC_ACQUIRE, __HIP_MEMORY_SCOPE_AGENT);
        }
        __syncthreads();
        if (threadIdx.x == 0)
            __hip_atomic_store(go, seq, __ATOMIC_RELEASE, __HIP_MEMORY_SCOPE_AGENT);
        __syncthreads();
    } else {
        if (threadIdx.x == 0){
            __hip_atomic_store(slots + (blockIdx.x-1)*SLOTP, seq,
                               __ATOMIC_RELEASE, __HIP_MEMORY_SCOPE_AGENT);
            while (__hip_atomic_load(go, __ATOMIC_RELAXED, __HIP_MEMORY_SCOPE_AGENT) < seq)
                __builtin_amdgcn_s_sleep(1);
            (void)__hip_atomic_load(go, __ATOMIC_ACQUIRE, __HIP_MEMORY_SCOPE_AGENT);
        }
        __syncthreads();
    }
}

// ---------------- LSTM v7: MFMA f16, W LDS-resident across all steps ----------------
// Block owns 4 units u0..u0+3 -> 16 gate-rows m = uu*4 + g.  W LDS [16][512] f16 staged once.
// h global f16 [buf][b 0..63][k 0..511] double-buffered; staged to LDS [64][512] per step.
// XOR swizzle on both arrays: byte ^= ((byte>>10 & 7) << 4)   (1 KB rows).
// Per wave: one 16-batch tile, 16x mfma_f32_16x16x32_f16 over K=512, f32 accum.
__global__ __launch_bounds__(256, 1) void k_lstm_v7(
    _Float16* __restrict__ hF, float* __restrict__ hqT,
    const float* __restrict__ xgT, const float* __restrict__ Whh,
    const float* __restrict__ h0, const float* __restrict__ c0,
    const int* __restrict__ lens, int* __restrict__ slots, int* __restrict__ go)
{
    __shared__ _Float16 Wl[16*512];    // 16 KB, swizzled
    __shared__ _Float16 hls[64*512];   // 64 KB, swizzled
    __shared__ float    gl[16*64];     // 4 KB

    int tid = threadIdx.x, bid = blockIdx.x;
    int u0  = bid * 4;
    int w   = tid >> 6, lane = tid & 63;

    // pointwise identity: all 256 threads = 4 units x 64 batch
    int pb = tid & 63, puu = tid >> 6;
    int pu = u0 + puu;
    float cprev = c0[pb*HIDD + pu];
    float hprev = h0[pb*HIDD + pu];
    int   mylen = lens[pb];

    // h(-1) -> buf1
    hF[(size_t)(1*64 + pb)*512 + pu] = (_Float16)hprev;
    if (bid == 0){                      // zero k-pad 500..511, both buffers
        for (int i = tid; i < 2*64*12; i += 256){
            int buf = i / 768, rem = i - buf*768;
            int b = rem / 12, k = 500 + rem % 12;
            hF[(size_t)(buf*64 + b)*512 + k] = (_Float16)0.f;
        }
    }
    // stage W slice to LDS once (f32 -> f16), swizzled
    for (int i = tid; i < 16*512; i += 256){
        int m = i >> 9, k = i & 511;
        int g = m & 3, uu = m >> 2;
        float v = (k < HIDD) ? Whh[(size_t)(g*HIDD + u0 + uu)*HIDD + k] : 0.f;
        int off = (i*2) ^ ((m & 7) << 4);
        Wl[off >> 1] = (_Float16)v;
    }
    gbar2(slots, go, 1);                // init barrier (also covers Wl via its syncthreads)

    const int mA = lane & 15, kb = lane >> 4;

    for (int t = 0; t < SEQL; ++t){
        // 1. stage h(t-1): 64 KB global -> LDS, swizzled (coalesced b128 both sides)
        const char* src = (const char*)(hF + (size_t)((t & 1) ^ 1)*64*512);
        #pragma unroll
        for (int c = 0; c < 16; ++c){
            int o = c*4096 + tid*16;
            float4 v = *(const float4*)(src + o);
            *(float4*)((char*)hls + (o ^ (((o >> 10) & 7) << 4))) = v;
        }
        __syncthreads();

        // 2. MFMA: wave w computes gate-rows[16] x batch-tile[w*16..+15]
        f32x4 acc = {0.f, 0.f, 0.f, 0.f};
        #pragma unroll
        for (int ks = 0; ks < 16; ++ks){
            int kByte = ks*64 + kb*16;                       // (ks*32 + kb*8) f16 elems
            int aOff = (mA*1024 + kByte) ^ ((mA & 7) << 4);
            int bRow = w*16 + mA;
            int bOff = (bRow*1024 + kByte) ^ ((bRow & 7) << 4);
            half8 af = *(const half8*)((const char*)Wl  + aOff);
            half8 bf = *(const half8*)((const char*)hls + bOff);
            acc = __builtin_amdgcn_mfma_f32_16x16x32_f16(af, bf, acc, 0, 0, 0);
        }
        // C layout: col = lane&15 (batch), row = (lane>>4)*4 + r (gate-row m)
        #pragma unroll
        for (int r = 0; r < 4; ++r)
            gl[(kb*4 + r)*64 + w*16 + mA] = acc[r];
        __syncthreads();

        // 3. pointwise (f32): gates = gl + xg; c,h update; write h(t) f16
        {
            float g4[4];
            #pragma unroll
            for (int g = 0; g < 4; ++g){
                float s = gl[(puu*4 + g)*64 + pb];
                s += xgT[(size_t)(g*HIDD + pu)*MCOL + t*64 + pb];
                g4[g] = s;
            }
            float si = sigmf(g4[0]), sf = sigmf(g4[1]);
            float tg = tanhf(g4[2]), so = sigmf(g4[3]);
            float cn = sf*cprev + si*tg;
            float hn = so*tanhf(cn);
            if (t < mylen){ cprev = cn; hprev = hn; }
            hF[(size_t)((t & 1)*64 + pb)*512 + pu] = (_Float16)hprev;
            if (t == SEQL-1) hqT[pu*64 + pb] = hprev;
        }
        if (t < SEQL-1) gbar2(slots, go, t + 2);   // last step: kernel-end fences
    }
}

// ---------------- q_part: qp[b][n] = sum_k hqT[k][b]*g1w[n][k] + g1b[n] ----------------
__global__ void k_qp(const float* __restrict__ hq, const float* __restrict__ g1w,
                     const float* __restrict__ g1b, float* __restrict__ qp)
{
    int idx = blockIdx.x*blockDim.x + threadIdx.x;
    if (idx >= BATCH*GHID) return;
    int b = idx / GHID, n = idx % GHID;
    const float* wr = g1w + n*548;
    float s = g1b[n];
    for (int k = 0; k < HIDD; ++k) s += hq[k*64 + b]*wr[k];
    qp[idx] = s;
}

// ---------------- i_part/j_part ----------------
__global__ void k_ipjp(const float* __restrict__ conv, const float* __restrict__ g1w,
                       float* __restrict__ ip, float* __restrict__ jp)
{
    int idx = blockIdx.x*blockDim.x + threadIdx.x;
    if (idx >= BATCH*NOBJ*GHID) return;
    int b = idx / (NOBJ*GHID);
    int rem = idx - b*(NOBJ*GHID);
    int o = rem / GHID, n = rem % GHID;
    const float* wj = g1w + n*548 + 500;
    const float* wi = g1w + n*548 + 524;
    float si = 0.f, sj = 0.f;
    #pragma unroll
    for (int c = 0; c < 24; ++c){
        float v = conv[((size_t)b*24 + c)*NOBJ + o];
        sj += v*wj[c];
        si += v*wi[c];
    }
    ip[idx] = si;
    jp[idx] = sj;
}

// ---------------- fused pair kernel: 2 i's x 64 j's per block ----------------
__global__ __launch_bounds__(256, 2) void k_pair(const float* __restrict__ qp, const float* __restrict__ ip,
              const float* __restrict__ jp, const float* __restrict__ g2w,
              const float* __restrict__ g2b, float* __restrict__ part)
{
    __shared__ float jpl[NOBJ][GHID+1];
    __shared__ float basel[2][GHID];
    __shared__ float g2wl[GHID*GHID];
    int b  = blockIdx.x >> 5;
    int ic = blockIdx.x & 31;
    int tid = threadIdx.x;
    for (int i = tid; i < NOBJ*GHID; i += 256){
        int j = i / GHID, k = i % GHID;
        jpl[j][k] = jp[((size_t)b*NOBJ + j)*GHID + k];
    }
    for (int i = tid; i < 2*GHID; i += 256){
        int ii = i / GHID, k = i % GHID;
        basel[ii][k] = qp[b*GHID + k] + ip[((size_t)b*NOBJ + ic*2 + ii)*GHID + k];
    }
    for (int i = tid; i < GHID*GHID; i += 256) g2wl[i] = g2w[i];
    __syncthreads();

    int j  = tid & 63;
    int nt = tid >> 6;
    float acc[2][25] = {};
    for (int k = 0; k < GHID; ++k){
        float jv = jpl[j][k];
        float a0 = fmaxf(basel[0][k] + jv, 0.f);
        float a1 = fmaxf(basel[1][k] + jv, 0.f);
        #pragma unroll
        for (int nn = 0; nn < 25; ++nn){
            float w = g2wl[(nt*25+nn)*GHID + k];
            acc[0][nn] += a0*w;
            acc[1][nn] += a1*w;
        }
    }
    #pragma unroll
    for (int nn = 0; nn < 25; ++nn){
        int n = nt*25 + nn;
        float gb = g2b[n];
        float s = fmaxf(acc[0][nn]+gb, 0.f) + fmaxf(acc[1][nn]+gb, 0.f);
        #pragma unroll
        for (int off = 32; off > 0; off >>= 1) s += __shfl_down(s, off);
        if ((tid & 63) == 0) part[(size_t)blockIdx.x*GHID + n] = s;
    }
}

// ---------------- final: reduce partials, f1, f2, log_softmax ----------------
__global__ __launch_bounds__(256) void k_final(const float* __restrict__ part, const float* __restrict__ f1w,
               const float* __restrict__ f1b, const float* __restrict__ f2w,
               const float* __restrict__ f2b, float* __restrict__ out)
{
    int b = blockIdx.x;
    int tid = threadIdx.x;
    __shared__ float gs[GHID];
    __shared__ float fh[GHID];
    __shared__ float lg[ANSN];
    __shared__ float red[4], red2[4];
    if (tid < GHID){
        float s = 0.f;
        for (int ic = 0; ic < 32; ++ic) s += part[((size_t)b*32 + ic)*GHID + tid];
        gs[tid] = s;
    }
    __syncthreads();
    if (tid < GHID){
        float s = f1b[tid];
        const float* w = f1w + tid*GHID;
        for (int k = 0; k < GHID; ++k) s += gs[k]*w[k];
        fh[tid] = fmaxf(s, 0.f);
    }
    __syncthreads();
    for (int n = tid; n < ANSN; n += 256){
        float s = f2b[n];
        const float* w = f2w + (size_t)n*GHID;
        for (int k = 0; k < GHID; ++k) s += fh[k]*w[k];
        lg[n] = fmaxf(s, 0.f);
    }
    __syncthreads();
    float mx = -1e30f;
    for (int n = tid; n < ANSN; n += 256) mx = fmaxf(mx, lg[n]);
    #pragma unroll
    for (int off = 32; off > 0; off >>= 1) mx = fmaxf(mx, __shfl_xor(mx, off));
    if ((tid & 63) == 0) red[tid >> 6] = mx;
    __syncthreads();
    mx = fmaxf(fmaxf(red[0], red[1]), fmaxf(red[2], red[3]));
    float se = 0.f;
    for (int n = tid; n < ANSN; n += 256) se += expf(lg[n]-mx);
    #pragma unroll
    for (int off = 32; off > 0; off >>= 1) se += __shfl_xor(se, off);
    if ((tid & 63) == 0) red2[tid >> 6] = se;
    __syncthreads();
    se = red2[0]+red2[1]+red2[2]+red2[3];
    float lse = logf(se);
    for (int n = tid; n < ANSN; n += 256) out[(size_t)b*ANSN + n] = lg[n] - mx - lse;
}

extern "C" void kernel_launch(void* const* d_in, const int* in_sizes, int n_in,
                              void* d_out, int out_size, void* d_ws, size_t ws_size,
                              hipStream_t stream)
{
    const int*   sent  = (const int*)  d_in[0];
    const float* conv  = (const float*)d_in[1];
    const int*   lens  = (const int*)  d_in[2];
    const float* table = (const float*)d_in[3];
    const float* W_ih  = (const float*)d_in[4];
    const float* W_hh  = (const float*)d_in[5];
    const float* b_ih  = (const float*)d_in[6];
    const float* b_hh  = (const float*)d_in[7];
    const float* h0    = (const float*)d_in[8];
    const float* c0    = (const float*)d_in[9];
    const float* g1_w  = (const float*)d_in[10];
    const float* g1_b  = (const float*)d_in[11];
    const float* g2_w  = (const float*)d_in[12];
    const float* g2_b  = (const float*)d_in[13];
    const float* f1_w  = (const float*)d_in[14];
    const float* f1_b  = (const float*)d_in[15];
    const float* f2_w  = (const float*)d_in[16];
    const float* f2_b  = (const float*)d_in[17];
    float* out = (float*)d_out;

    float* ws   = (float*)d_ws;
    int*   go   = (int*)d_ws;                          // 1 word (own line)
    int*   slots= (int*)d_ws + SLOTP;                  // 124 slots * 32 ints
    _Float16* hF = (_Float16*)(ws + 16384);            // 2*64*512 f16 = 128 KB (32768 floats)
    float* hqT  = ws + 16384 + 32768;                  // 500*64
    float* embT = hqT + HIDD*64;                       // 300*2048
    float* xgT  = embT + (size_t)EMBD*MCOL;            // 2000*2048
    float* qp   = xgT  + (size_t)4*HIDD*MCOL;          // 64*100
    float* ip   = qp   + BATCH*GHID;                   // 64*64*100
    float* jp   = ip   + BATCH*NOBJ*GHID;
    float* part = jp   + BATCH*NOBJ*GHID;              // 2048*100

    // 0. zero barrier region (deterministic across graph replays)
    hipMemsetAsync(go, 0, 16384*sizeof(float), stream);

    // 1. embedding gather, transposed
    {
        dim3 g(3, SEQL);
        k_embT<<<g, 256, 0, stream>>>(sent, table, embT);
    }

    // 2. xgT = W_ih @ embT + (b_ih+b_hh)
    {
        dim3 g(MCOL/64, (4*HIDD + 63)/64);
        k_gemm_nn<<<g, 256, 0, stream>>>(W_ih, embT, b_ih, b_hh, xgT,
                                         4*HIDD, MCOL, EMBD);
    }

    // 3. MFMA LSTM, 125 blocks, distributed barrier (cooperative for residency)
    {
        _Float16* hF_p = hF; float* hqT_p = hqT;
        const float* xgT_p = xgT; const float* Whh_p = W_hh;
        const float* h0_p = h0; const float* c0_p = c0; const int* lens_p = lens;
        int* slots_p = slots; int* go_p = go;
        void* kargs[] = { (void*)&hF_p, (void*)&hqT_p, (void*)&xgT_p, (void*)&Whh_p,
                          (void*)&h0_p, (void*)&c0_p, (void*)&lens_p,
                          (void*)&slots_p, (void*)&go_p };
        hipLaunchCooperativeKernel((const void*)k_lstm_v7, dim3(VBLK), dim3(256),
                                   kargs, 0, stream);
    }

    // 4. g_mlp layer-1 partials
    k_qp<<<(BATCH*GHID + 255)/256, 256, 0, stream>>>(hqT, g1_w, g1_b, qp);
    k_ipjp<<<(BATCH*NOBJ*GHID + 255)/256, 256, 0, stream>>>(conv, g1_w, ip, jp);

    // 5. fused pair kernel (2 i's per block) -> partial sums
    k_pair<<<BATCH*32, 256, 0, stream>>>(qp, ip, jp, g2_w, g2_b, part);

    // 6. final MLP + log_softmax
    k_final<<<BATCH, 256, 0, stream>>>(part, f1_w, f1_b, f2_w, f2_b, out);
}

// Round 8
// 489.919 us; speedup vs baseline: 2.3822x; 1.2334x over previous
//
#include <hip/hip_runtime.h>
#include <cmath>

#define BATCH 64
#define SEQL  32
#define EMBD  300
#define HIDD  500
#define NOBJ  64
#define GHID  100
#define ANSN  1000
#define MCOL  2048   // t*64+b column dimension

// LSTM v8 partition: 4 batch-groups x 25 unit-blocks
#define GRP    4
#define GBATCH 16
#define BPG    25
#define UPB8   20
#define NBLK   (GRP*BPG)   // 100
#define SLOTP  32          // slot padding in ints (128 B)

typedef _Float16 half8 __attribute__((ext_vector_type(8)));
typedef float    f32x4 __attribute__((ext_vector_type(4)));

__device__ __forceinline__ float sigmf(float x){ return 1.f/(1.f+expf(-x)); }

// sc1 (coherence-point) primitives: RELAXED agent-scope atomics, no cache-wide fences
__device__ __forceinline__ float2 ld_cc2(const unsigned long long* p){
    union { unsigned long long u; float2 f; } c;
    c.u = __hip_atomic_load(p, __ATOMIC_RELAXED, __HIP_MEMORY_SCOPE_AGENT);
    return c.f;
}
__device__ __forceinline__ void st_cc8(_Float16* p, unsigned long long v){
    __hip_atomic_store((unsigned long long*)p, v, __ATOMIC_RELAXED, __HIP_MEMORY_SCOPE_AGENT);
}

// ---------------- embT[k][t*64+b] = table[sent[b*32+t]][k] ----------------
__global__ void k_embT(const int* __restrict__ sent, const float* __restrict__ table,
                       float* __restrict__ embT)
{
    __shared__ float T[64][101];
    int t  = blockIdx.y;
    int k0 = blockIdx.x * 100;
    int tid = threadIdx.x;
    for (int i = tid; i < 64*100; i += 256){
        int b = i / 100, k = i - b*100;
        T[b][k] = table[(size_t)sent[b*SEQL + t]*EMBD + k0 + k];
    }
    __syncthreads();
    for (int i = tid; i < 100*64; i += 256){
        int k = i >> 6, b = i & 63;
        embT[(size_t)(k0+k)*MCOL + t*64 + b] = T[b][k];
    }
}

// ---------------- NN GEMM: C[n][m] = sum_k A[n][k]*B[k][m] + bias0[n]+bias1[n] ----------------
__global__ __launch_bounds__(256) void k_gemm_nn(const float* __restrict__ A, const float* __restrict__ B,
                 const float* __restrict__ bias0, const float* __restrict__ bias1,
                 float* __restrict__ C, int N, int M, int K)
{
    __shared__ float As[16][65];
    __shared__ float Bs[16][65];
    int n0 = blockIdx.y*64, m0 = blockIdx.x*64;
    int tid = threadIdx.x, tx = tid & 15, ty = tid >> 4;
    float acc[4][4] = {};
    for (int k0 = 0; k0 < K; k0 += 16){
        for (int i = tid; i < 64*16; i += 256){
            int n = i >> 4, k = i & 15;
            As[k][n] = (n0+n < N && k0+k < K) ? A[(size_t)(n0+n)*K + k0+k] : 0.f;
        }
        for (int i = tid; i < 16*64; i += 256){
            int k = i >> 6, m = i & 63;
            Bs[k][m] = (k0+k < K) ? B[(size_t)(k0+k)*M + m0+m] : 0.f;
        }
        __syncthreads();
        #pragma unroll
        for (int kk = 0; kk < 16; ++kk){
            float a[4], b[4];
            #pragma unroll
            for (int i=0;i<4;i++) a[i] = As[kk][ty*4+i];
            #pragma unroll
            for (int j=0;j<4;j++) b[j] = Bs[kk][tx*4+j];
            #pragma unroll
            for (int i=0;i<4;i++)
                #pragma unroll
                for (int j=0;j<4;j++) acc[i][j] += a[i]*b[j];
        }
        __syncthreads();
    }
    #pragma unroll
    for (int i=0;i<4;i++){
        int n = n0 + ty*4 + i;
        if (n >= N) continue;
        float bsum = bias0[n] + bias1[n];
        float4 v;
        v.x = acc[i][0]+bsum; v.y = acc[i][1]+bsum; v.z = acc[i][2]+bsum; v.w = acc[i][3]+bsum;
        *(float4*)(C + (size_t)n*M + m0 + tx*4) = v;
    }
}

// ---------------- group-local all-to-all barrier (one hop, fence-free) ----------------
// Entry __syncthreads drains vmcnt(0): prior sc1 stores are acked at the coherence point
// before tid0's slot store. Polls are sc1 relaxed; no acquire/release cache maintenance.
__device__ __forceinline__ void gbarA(int* slots, int grp, int ub, int seq)
{
    __syncthreads();
    if (threadIdx.x == 0)
        __hip_atomic_store(slots + (grp*BPG + ub)*SLOTP, seq,
                           __ATOMIC_RELAXED, __HIP_MEMORY_SCOPE_AGENT);
    if (threadIdx.x < BPG){
        int* s = slots + (grp*BPG + threadIdx.x)*SLOTP;
        while (__hip_atomic_load(s, __ATOMIC_RELAXED, __HIP_MEMORY_SCOPE_AGENT) < seq)
            __builtin_amdgcn_s_sleep(1);
    }
    asm volatile("" ::: "memory");
    __syncthreads();
}

// ---------------- LSTM v8: MFMA f16, batch-grouped, sc1 h exchange ----------------
// Block (grp, ub): 20 units u0=ub*20, batch rows grp*16..+15.  320 threads (5 waves).
// Wl [80 rows=g*20+uu][512 k] f16, LDS-resident, XOR-swizzled 1KB rows.
// hF global f16 [buf][g][b 0..15][k 0..511]; staged to hls [16][512] per step (sc1 b64).
// Waves 0..3: k-quarter x 5 row-tiles -> gl partials; wave 4 idles MFMA, joins pointwise.
__global__ __launch_bounds__(320, 1) void k_lstm_v8(
    _Float16* __restrict__ hF, float* __restrict__ hqT,
    const float* __restrict__ xgT, const float* __restrict__ Whh,
    const float* __restrict__ h0, const float* __restrict__ c0,
    const int* __restrict__ lens, int* __restrict__ slots)
{
    __shared__ _Float16 Wl[80*512];    // 80 KB
    __shared__ _Float16 hls[16*512];   // 16 KB
    __shared__ float    gl[4*80*16];   // 20 KB
    __shared__ _Float16 hout[16*UPB8]; // 640 B

    int tid = threadIdx.x, bid = blockIdx.x;
    int grp = bid / BPG, ub = bid - grp*BPG;
    int u0  = ub * UPB8;
    int w   = tid >> 6, lane = tid & 63;

    // pointwise identity: 320 threads = 20 units x 16 batch
    int pb  = tid & 15, puu = tid >> 4;        // puu 0..19
    int pu  = u0 + puu;
    int gb  = grp*GBATCH + pb;                 // global batch row
    float cprev = c0[gb*HIDD + pu];
    float hprev = h0[gb*HIDD + pu];
    int   mylen = lens[gb];
    hout[pb*UPB8 + puu] = (_Float16)hprev;

    // stage W slice -> LDS once (f32->f16), swizzled; row m = g*20+uu
    for (int i = tid; i < 80*512; i += 320){
        int m = i >> 9, k = i & 511;
        int g = m / UPB8, uu = m - g*UPB8;
        float v = (k < HIDD) ? Whh[(size_t)(g*HIDD + u0 + uu)*HIDD + k] : 0.f;
        int off = (i*2) ^ ((m & 7) << 4);
        *(_Float16*)((char*)Wl + off) = (_Float16)v;
    }
    __syncthreads();
    // h(-1) -> buf1 via sc1 u64 stores (LDS-packed)
    if (tid < 80){
        int b = tid / 5, q = tid - (tid/5)*5;
        unsigned long long v = *(const unsigned long long*)((const char*)hout + b*40 + q*8);
        st_cc8(hF + ((size_t)(1*GRP + grp)*GBATCH + b)*512 + u0 + q*4, v);
    }
    // zero k-pad 500..511, both buffers (ub==0 blocks; never written again)
    if (ub == 0 && tid >= 128 && tid < 224){
        int j = tid - 128;                // 0..95 = buf(2) x b(16) x q(3)
        int buf = j / 48, r = j - buf*48;
        int b = r / 3, q = r - (r/3)*3;
        st_cc8(hF + ((size_t)(buf*GRP + grp)*GBATCH + b)*512 + 500 + q*4, 0ULL);
    }
    gbarA(slots, grp, ub, 1);

    const int mA = lane & 15, kb = lane >> 4;

    for (int t = 0; t < SEQL; ++t){
        // 1. stage h(t-1) group slice: 16KB, sc1 b64 loads -> swizzled LDS
        {
            const char* src = (const char*)(hF + (size_t)(((t&1)^1)*GRP + grp)*GBATCH*512);
            for (int idx = tid; idx < 2048; idx += 320){
                int o = idx*8;
                float2 v = ld_cc2((const unsigned long long*)(src + o));
                *(float2*)((char*)hls + (o ^ (((o >> 10) & 7) << 4))) = v;
            }
        }
        __syncthreads();

        // 2. MFMA (waves 0..3): k-quarter ks=w*4..+3, row-tiles rt=0..4
        if (w < 4){
            f32x4 acc[5] = {};
            half8 bf[4];
            #pragma unroll
            for (int ks4 = 0; ks4 < 4; ++ks4){
                int kByte = (w*4 + ks4)*64 + kb*16;
                int bOff  = (mA*1024 + kByte) ^ ((mA & 7) << 4);
                bf[ks4] = *(const half8*)((const char*)hls + bOff);
            }
            #pragma unroll
            for (int rt = 0; rt < 5; ++rt){
                #pragma unroll
                for (int ks4 = 0; ks4 < 4; ++ks4){
                    int kByte = (w*4 + ks4)*64 + kb*16;
                    int m = rt*16 + mA;
                    int aOff = (m*1024 + kByte) ^ ((m & 7) << 4);
                    half8 af = *(const half8*)((const char*)Wl + aOff);
                    acc[rt] = __builtin_amdgcn_mfma_f32_16x16x32_f16(af, bf[ks4], acc[rt], 0, 0, 0);
                }
            }
            // C layout: col = lane&15 (batch), row-in-tile = kb*4 + r
            #pragma unroll
            for (int rt = 0; rt < 5; ++rt)
                #pragma unroll
                for (int r = 0; r < 4; ++r)
                    gl[(w*80 + rt*16 + kb*4 + r)*16 + mA] = acc[rt][r];
        }
        __syncthreads();

        // 3. pointwise (all 320 threads): sum 4 wave-partials + xg; update c,h
        {
            float g4[4];
            #pragma unroll
            for (int g = 0; g < 4; ++g){
                int row = g*UPB8 + puu;
                float s = gl[(0*80 + row)*16 + pb] + gl[(1*80 + row)*16 + pb]
                        + gl[(2*80 + row)*16 + pb] + gl[(3*80 + row)*16 + pb];
                s += xgT[(size_t)(g*HIDD + pu)*MCOL + t*64 + gb];
                g4[g] = s;
            }
            float si = sigmf(g4[0]), sf = sigmf(g4[1]);
            float tg = tanhf(g4[2]), so = sigmf(g4[3]);
            float cn = sf*cprev + si*tg;
            float hn = so*tanhf(cn);
            if (t < mylen){ cprev = cn; hprev = hn; }
            hout[pb*UPB8 + puu] = (_Float16)hprev;
            if (t == SEQL-1) hqT[pu*64 + gb] = hprev;
        }
        if (t < SEQL-1){
            __syncthreads();               // hout complete in LDS
            if (tid < 80){                 // pack -> sc1 u64 stores
                int b = tid / 5, q = tid - (tid/5)*5;
                unsigned long long v = *(const unsigned long long*)((const char*)hout + b*40 + q*8);
                st_cc8(hF + ((size_t)((t&1)*GRP + grp)*GBATCH + b)*512 + u0 + q*4, v);
            }
            gbarA(slots, grp, ub, t + 2);  // entry sync drains vmcnt -> stores acked
        }
    }
}

// ---------------- q_part: qp[b][n] = sum_k hqT[k][b]*g1w[n][k] + g1b[n] ----------------
__global__ void k_qp(const float* __restrict__ hq, const float* __restrict__ g1w,
                     const float* __restrict__ g1b, float* __restrict__ qp)
{
    int idx = blockIdx.x*blockDim.x + threadIdx.x;
    if (idx >= BATCH*GHID) return;
    int b = idx / GHID, n = idx % GHID;
    const float* wr = g1w + n*548;
    float s = g1b[n];
    for (int k = 0; k < HIDD; ++k) s += hq[k*64 + b]*wr[k];
    qp[idx] = s;
}

// ---------------- i_part/j_part ----------------
__global__ void k_ipjp(const float* __restrict__ conv, const float* __restrict__ g1w,
                       float* __restrict__ ip, float* __restrict__ jp)
{
    int idx = blockIdx.x*blockDim.x + threadIdx.x;
    if (idx >= BATCH*NOBJ*GHID) return;
    int b = idx / (NOBJ*GHID);
    int rem = idx - b*(NOBJ*GHID);
    int o = rem / GHID, n = rem % GHID;
    const float* wj = g1w + n*548 + 500;
    const float* wi = g1w + n*548 + 524;
    float si = 0.f, sj = 0.f;
    #pragma unroll
    for (int c = 0; c < 24; ++c){
        float v = conv[((size_t)b*24 + c)*NOBJ + o];
        sj += v*wj[c];
        si += v*wi[c];
    }
    ip[idx] = si;
    jp[idx] = sj;
}

// ---------------- fused pair kernel: 2 i's x 64 j's per block ----------------
__global__ __launch_bounds__(256, 2) void k_pair(const float* __restrict__ qp, const float* __restrict__ ip,
              const float* __restrict__ jp, const float* __restrict__ g2w,
              const float* __restrict__ g2b, float* __restrict__ part)
{
    __shared__ float jpl[NOBJ][GHID+1];
    __shared__ float basel[2][GHID];
    __shared__ float g2wl[GHID*GHID];
    int b  = blockIdx.x >> 5;
    int ic = blockIdx.x & 31;
    int tid = threadIdx.x;
    for (int i = tid; i < NOBJ*GHID; i += 256){
        int j = i / GHID, k = i % GHID;
        jpl[j][k] = jp[((size_t)b*NOBJ + j)*GHID + k];
    }
    for (int i = tid; i < 2*GHID; i += 256){
        int ii = i / GHID, k = i % GHID;
        basel[ii][k] = qp[b*GHID + k] + ip[((size_t)b*NOBJ + ic*2 + ii)*GHID + k];
    }
    for (int i = tid; i < GHID*GHID; i += 256) g2wl[i] = g2w[i];
    __syncthreads();

    int j  = tid & 63;
    int nt = tid >> 6;
    float acc[2][25] = {};
    for (int k = 0; k < GHID; ++k){
        float jv = jpl[j][k];
        float a0 = fmaxf(basel[0][k] + jv, 0.f);
        float a1 = fmaxf(basel[1][k] + jv, 0.f);
        #pragma unroll
        for (int nn = 0; nn < 25; ++nn){
            float w = g2wl[(nt*25+nn)*GHID + k];
            acc[0][nn] += a0*w;
            acc[1][nn] += a1*w;
        }
    }
    #pragma unroll
    for (int nn = 0; nn < 25; ++nn){
        int n = nt*25 + nn;
        float gb = g2b[n];
        float s = fmaxf(acc[0][nn]+gb, 0.f) + fmaxf(acc[1][nn]+gb, 0.f);
        #pragma unroll
        for (int off = 32; off > 0; off >>= 1) s += __shfl_down(s, off);
        if ((tid & 63) == 0) part[(size_t)blockIdx.x*GHID + n] = s;
    }
}

// ---------------- final: reduce partials, f1, f2, log_softmax ----------------
__global__ __launch_bounds__(256) void k_final(const float* __restrict__ part, const float* __restrict__ f1w,
               const float* __restrict__ f1b, const float* __restrict__ f2w,
               const float* __restrict__ f2b, float* __restrict__ out)
{
    int b = blockIdx.x;
    int tid = threadIdx.x;
    __shared__ float gs[GHID];
    __shared__ float fh[GHID];
    __shared__ float lg[ANSN];
    __shared__ float red[4], red2[4];
    if (tid < GHID){
        float s = 0.f;
        for (int ic = 0; ic < 32; ++ic) s += part[((size_t)b*32 + ic)*GHID + tid];
        gs[tid] = s;
    }
    __syncthreads();
    if (tid < GHID){
        float s = f1b[tid];
        const float* w = f1w + tid*GHID;
        for (int k = 0; k < GHID; ++k) s += gs[k]*w[k];
        fh[tid] = fmaxf(s, 0.f);
    }
    __syncthreads();
    for (int n = tid; n < ANSN; n += 256){
        float s = f2b[n];
        const float* w = f2w + (size_t)n*GHID;
        for (int k = 0; k < GHID; ++k) s += fh[k]*w[k];
        lg[n] = fmaxf(s, 0.f);
    }
    __syncthreads();
    float mx = -1e30f;
    for (int n = tid; n < ANSN; n += 256) mx = fmaxf(mx, lg[n]);
    #pragma unroll
    for (int off = 32; off > 0; off >>= 1) mx = fmaxf(mx, __shfl_xor(mx, off));
    if ((tid & 63) == 0) red[tid >> 6] = mx;
    __syncthreads();
    mx = fmaxf(fmaxf(red[0], red[1]), fmaxf(red[2], red[3]));
    float se = 0.f;
    for (int n = tid; n < ANSN; n += 256) se += expf(lg[n]-mx);
    #pragma unroll
    for (int off = 32; off > 0; off >>= 1) se += __shfl_xor(se, off);
    if ((tid & 63) == 0) red2[tid >> 6] = se;
    __syncthreads();
    se = red2[0]+red2[1]+red2[2]+red2[3];
    float lse = logf(se);
    for (int n = tid; n < ANSN; n += 256) out[(size_t)b*ANSN + n] = lg[n] - mx - lse;
}

extern "C" void kernel_launch(void* const* d_in, const int* in_sizes, int n_in,
                              void* d_out, int out_size, void* d_ws, size_t ws_size,
                              hipStream_t stream)
{
    const int*   sent  = (const int*)  d_in[0];
    const float* conv  = (const float*)d_in[1];
    const int*   lens  = (const int*)  d_in[2];
    const float* table = (const float*)d_in[3];
    const float* W_ih  = (const float*)d_in[4];
    const float* W_hh  = (const float*)d_in[5];
    const float* b_ih  = (const float*)d_in[6];
    const float* b_hh  = (const float*)d_in[7];
    const float* h0    = (const float*)d_in[8];
    const float* c0    = (const float*)d_in[9];
    const float* g1_w  = (const float*)d_in[10];
    const float* g1_b  = (const float*)d_in[11];
    const float* g2_w  = (const float*)d_in[12];
    const float* g2_b  = (const float*)d_in[13];
    const float* f1_w  = (const float*)d_in[14];
    const float* f1_b  = (const float*)d_in[15];
    const float* f2_w  = (const float*)d_in[16];
    const float* f2_b  = (const float*)d_in[17];
    float* out = (float*)d_out;

    float* ws   = (float*)d_ws;
    int*   slots= (int*)d_ws;                          // 100 slots * 32 ints
    _Float16* hF = (_Float16*)(ws + 16384);            // 2*4*16*512 f16 = 128 KB
    float* hqT  = ws + 16384 + 32768;                  // 500*64
    float* embT = hqT + HIDD*64;                       // 300*2048
    float* xgT  = embT + (size_t)EMBD*MCOL;            // 2000*2048
    float* qp   = xgT  + (size_t)4*HIDD*MCOL;          // 64*100
    float* ip   = qp   + BATCH*GHID;                   // 64*64*100
    float* jp   = ip   + BATCH*NOBJ*GHID;
    float* part = jp   + BATCH*NOBJ*GHID;              // 2048*100

    // 0. zero barrier region (deterministic across graph replays)
    hipMemsetAsync(slots, 0, 16384*sizeof(float), stream);

    // 1. embedding gather, transposed
    {
        dim3 g(3, SEQL);
        k_embT<<<g, 256, 0, stream>>>(sent, table, embT);
    }

    // 2. xgT = W_ih @ embT + (b_ih+b_hh)
    {
        dim3 g(MCOL/64, (4*HIDD + 63)/64);
        k_gemm_nn<<<g, 256, 0, stream>>>(W_ih, embT, b_ih, b_hh, xgT,
                                         4*HIDD, MCOL, EMBD);
    }

    // 3. MFMA LSTM, 100 blocks (4 groups x 25), group-local one-hop barriers
    {
        _Float16* hF_p = hF; float* hqT_p = hqT;
        const float* xgT_p = xgT; const float* Whh_p = W_hh;
        const float* h0_p = h0; const float* c0_p = c0; const int* lens_p = lens;
        int* slots_p = slots;
        void* kargs[] = { (void*)&hF_p, (void*)&hqT_p, (void*)&xgT_p, (void*)&Whh_p,
                          (void*)&h0_p, (void*)&c0_p, (void*)&lens_p, (void*)&slots_p };
        hipLaunchCooperativeKernel((const void*)k_lstm_v8, dim3(NBLK), dim3(320),
                                   kargs, 0, stream);
    }

    // 4. g_mlp layer-1 partials
    k_qp<<<(BATCH*GHID + 255)/256, 256, 0, stream>>>(hqT, g1_w, g1_b, qp);
    k_ipjp<<<(BATCH*NOBJ*GHID + 255)/256, 256, 0, stream>>>(conv, g1_w, ip, jp);

    // 5. fused pair kernel (2 i's per block) -> partial sums
    k_pair<<<BATCH*32, 256, 0, stream>>>(qp, ip, jp, g2_w, g2_b, part);

    // 6. final MLP + log_softmax
    k_final<<<BATCH, 256, 0, stream>>>(part, f1_w, f1_b, f2_w, f2_b, out);
}

// Round 9
// 382.622 us; speedup vs baseline: 3.0503x; 1.2804x over previous
//
#include <hip/hip_runtime.h>
#include <cmath>

#define BATCH 64
#define SEQL  32
#define EMBD  300
#define HIDD  500
#define NOBJ  64
#define GHID  100
#define ANSN  1000
#define MCOL  2048   // t*64+b column dimension

// LSTM v8 partition: 4 batch-groups x 25 unit-blocks
#define GRP    4
#define GBATCH 16
#define BPG    25
#define UPB8   20
#define NBLK   (GRP*BPG)   // 100
#define SLOTP  32          // slot padding in ints (128 B)

typedef _Float16 half8 __attribute__((ext_vector_type(8)));
typedef float    f32x4 __attribute__((ext_vector_type(4)));

__device__ __forceinline__ float sigmf(float x){ return 1.f/(1.f+expf(-x)); }

// sc1 (coherence-point) primitives: RELAXED agent-scope atomics, no cache-wide fences
__device__ __forceinline__ float2 ld_cc2(const unsigned long long* p){
    union { unsigned long long u; float2 f; } c;
    c.u = __hip_atomic_load(p, __ATOMIC_RELAXED, __HIP_MEMORY_SCOPE_AGENT);
    return c.f;
}
__device__ __forceinline__ void st_cc8(_Float16* p, unsigned long long v){
    __hip_atomic_store((unsigned long long*)p, v, __ATOMIC_RELAXED, __HIP_MEMORY_SCOPE_AGENT);
}

// ---------------- embT[k][t*64+b] = table[sent[b*32+t]][k] ----------------
__global__ void k_embT(const int* __restrict__ sent, const float* __restrict__ table,
                       float* __restrict__ embT)
{
    __shared__ float T[64][101];
    int t  = blockIdx.y;
    int k0 = blockIdx.x * 100;
    int tid = threadIdx.x;
    for (int i = tid; i < 64*100; i += 256){
        int b = i / 100, k = i - b*100;
        T[b][k] = table[(size_t)sent[b*SEQL + t]*EMBD + k0 + k];
    }
    __syncthreads();
    for (int i = tid; i < 100*64; i += 256){
        int k = i >> 6, b = i & 63;
        embT[(size_t)(k0+k)*MCOL + t*64 + b] = T[b][k];
    }
}

// ---------------- NN GEMM: C[n][m] = sum_k A[n][k]*B[k][m] + bias0[n]+bias1[n] ----------------
__global__ __launch_bounds__(256) void k_gemm_nn(const float* __restrict__ A, const float* __restrict__ B,
                 const float* __restrict__ bias0, const float* __restrict__ bias1,
                 float* __restrict__ C, int N, int M, int K)
{
    __shared__ float As[16][65];
    __shared__ float Bs[16][65];
    int n0 = blockIdx.y*64, m0 = blockIdx.x*64;
    int tid = threadIdx.x, tx = tid & 15, ty = tid >> 4;
    float acc[4][4] = {};
    for (int k0 = 0; k0 < K; k0 += 16){
        for (int i = tid; i < 64*16; i += 256){
            int n = i >> 4, k = i & 15;
            As[k][n] = (n0+n < N && k0+k < K) ? A[(size_t)(n0+n)*K + k0+k] : 0.f;
        }
        for (int i = tid; i < 16*64; i += 256){
            int k = i >> 6, m = i & 63;
            Bs[k][m] = (k0+k < K) ? B[(size_t)(k0+k)*M + m0+m] : 0.f;
        }
        __syncthreads();
        #pragma unroll
        for (int kk = 0; kk < 16; ++kk){
            float a[4], b[4];
            #pragma unroll
            for (int i=0;i<4;i++) a[i] = As[kk][ty*4+i];
            #pragma unroll
            for (int j=0;j<4;j++) b[j] = Bs[kk][tx*4+j];
            #pragma unroll
            for (int i=0;i<4;i++)
                #pragma unroll
                for (int j=0;j<4;j++) acc[i][j] += a[i]*b[j];
        }
        __syncthreads();
    }
    #pragma unroll
    for (int i=0;i<4;i++){
        int n = n0 + ty*4 + i;
        if (n >= N) continue;
        float bsum = bias0[n] + bias1[n];
        float4 v;
        v.x = acc[i][0]+bsum; v.y = acc[i][1]+bsum; v.z = acc[i][2]+bsum; v.w = acc[i][3]+bsum;
        *(float4*)(C + (size_t)n*M + m0 + tx*4) = v;
    }
}

// ---------------- group-local all-to-all barrier (one hop, fence-free) ----------------
__device__ __forceinline__ void gbarA(int* slots, int grp, int ub, int seq)
{
    __syncthreads();
    if (threadIdx.x == 0)
        __hip_atomic_store(slots + (grp*BPG + ub)*SLOTP, seq,
                           __ATOMIC_RELAXED, __HIP_MEMORY_SCOPE_AGENT);
    if (threadIdx.x < BPG){
        int* s = slots + (grp*BPG + threadIdx.x)*SLOTP;
        while (__hip_atomic_load(s, __ATOMIC_RELAXED, __HIP_MEMORY_SCOPE_AGENT) < seq)
            __builtin_amdgcn_s_sleep(1);
    }
    asm volatile("" ::: "memory");
    __syncthreads();
}

// ---------------- LSTM v8: MFMA f16, batch-grouped, sc1 h exchange ----------------
__global__ __launch_bounds__(320, 1) void k_lstm_v8(
    _Float16* __restrict__ hF, float* __restrict__ hqT,
    const float* __restrict__ xgT, const float* __restrict__ Whh,
    const float* __restrict__ h0, const float* __restrict__ c0,
    const int* __restrict__ lens, int* __restrict__ slots)
{
    __shared__ _Float16 Wl[80*512];    // 80 KB
    __shared__ _Float16 hls[16*512];   // 16 KB
    __shared__ float    gl[4*80*16];   // 20 KB
    __shared__ _Float16 hout[16*UPB8]; // 640 B

    int tid = threadIdx.x, bid = blockIdx.x;
    int grp = bid / BPG, ub = bid - grp*BPG;
    int u0  = ub * UPB8;
    int w   = tid >> 6, lane = tid & 63;

    int pb  = tid & 15, puu = tid >> 4;        // puu 0..19
    int pu  = u0 + puu;
    int gb  = grp*GBATCH + pb;                 // global batch row
    float cprev = c0[gb*HIDD + pu];
    float hprev = h0[gb*HIDD + pu];
    int   mylen = lens[gb];
    hout[pb*UPB8 + puu] = (_Float16)hprev;

    for (int i = tid; i < 80*512; i += 320){
        int m = i >> 9, k = i & 511;
        int g = m / UPB8, uu = m - g*UPB8;
        float v = (k < HIDD) ? Whh[(size_t)(g*HIDD + u0 + uu)*HIDD + k] : 0.f;
        int off = (i*2) ^ ((m & 7) << 4);
        *(_Float16*)((char*)Wl + off) = (_Float16)v;
    }
    __syncthreads();
    if (tid < 80){
        int b = tid / 5, q = tid - (tid/5)*5;
        unsigned long long v = *(const unsigned long long*)((const char*)hout + b*40 + q*8);
        st_cc8(hF + ((size_t)(1*GRP + grp)*GBATCH + b)*512 + u0 + q*4, v);
    }
    if (ub == 0 && tid >= 128 && tid < 224){
        int j = tid - 128;
        int buf = j / 48, r = j - buf*48;
        int b = r / 3, q = r - (r/3)*3;
        st_cc8(hF + ((size_t)(buf*GRP + grp)*GBATCH + b)*512 + 500 + q*4, 0ULL);
    }
    gbarA(slots, grp, ub, 1);

    const int mA = lane & 15, kb = lane >> 4;

    for (int t = 0; t < SEQL; ++t){
        {
            const char* src = (const char*)(hF + (size_t)(((t&1)^1)*GRP + grp)*GBATCH*512);
            for (int idx = tid; idx < 2048; idx += 320){
                int o = idx*8;
                float2 v = ld_cc2((const unsigned long long*)(src + o));
                *(float2*)((char*)hls + (o ^ (((o >> 10) & 7) << 4))) = v;
            }
        }
        __syncthreads();

        if (w < 4){
            f32x4 acc[5] = {};
            half8 bf[4];
            #pragma unroll
            for (int ks4 = 0; ks4 < 4; ++ks4){
                int kByte = (w*4 + ks4)*64 + kb*16;
                int bOff  = (mA*1024 + kByte) ^ ((mA & 7) << 4);
                bf[ks4] = *(const half8*)((const char*)hls + bOff);
            }
            #pragma unroll
            for (int rt = 0; rt < 5; ++rt){
                #pragma unroll
                for (int ks4 = 0; ks4 < 4; ++ks4){
                    int kByte = (w*4 + ks4)*64 + kb*16;
                    int m = rt*16 + mA;
                    int aOff = (m*1024 + kByte) ^ ((m & 7) << 4);
                    half8 af = *(const half8*)((const char*)Wl + aOff);
                    acc[rt] = __builtin_amdgcn_mfma_f32_16x16x32_f16(af, bf[ks4], acc[rt], 0, 0, 0);
                }
            }
            #pragma unroll
            for (int rt = 0; rt < 5; ++rt)
                #pragma unroll
                for (int r = 0; r < 4; ++r)
                    gl[(w*80 + rt*16 + kb*4 + r)*16 + mA] = acc[rt][r];
        }
        __syncthreads();

        {
            float g4[4];
            #pragma unroll
            for (int g = 0; g < 4; ++g){
                int row = g*UPB8 + puu;
                float s = gl[(0*80 + row)*16 + pb] + gl[(1*80 + row)*16 + pb]
                        + gl[(2*80 + row)*16 + pb] + gl[(3*80 + row)*16 + pb];
                s += xgT[(size_t)(g*HIDD + pu)*MCOL + t*64 + gb];
                g4[g] = s;
            }
            float si = sigmf(g4[0]), sf = sigmf(g4[1]);
            float tg = tanhf(g4[2]), so = sigmf(g4[3]);
            float cn = sf*cprev + si*tg;
            float hn = so*tanhf(cn);
            if (t < mylen){ cprev = cn; hprev = hn; }
            hout[pb*UPB8 + puu] = (_Float16)hprev;
            if (t == SEQL-1) hqT[pu*64 + gb] = hprev;
        }
        if (t < SEQL-1){
            __syncthreads();
            if (tid < 80){
                int b = tid / 5, q = tid - (tid/5)*5;
                unsigned long long v = *(const unsigned long long*)((const char*)hout + b*40 + q*8);
                st_cc8(hF + ((size_t)((t&1)*GRP + grp)*GBATCH + b)*512 + u0 + q*4, v);
            }
            gbarA(slots, grp, ub, t + 2);
        }
    }
}

// ---------------- q_part ----------------
__global__ void k_qp(const float* __restrict__ hq, const float* __restrict__ g1w,
                     const float* __restrict__ g1b, float* __restrict__ qp)
{
    int idx = blockIdx.x*blockDim.x + threadIdx.x;
    if (idx >= BATCH*GHID) return;
    int b = idx / GHID, n = idx % GHID;
    const float* wr = g1w + n*548;
    float s = g1b[n];
    for (int k = 0; k < HIDD; ++k) s += hq[k*64 + b]*wr[k];
    qp[idx] = s;
}

// ---------------- i_part/j_part ----------------
__global__ void k_ipjp(const float* __restrict__ conv, const float* __restrict__ g1w,
                       float* __restrict__ ip, float* __restrict__ jp)
{
    int idx = blockIdx.x*blockDim.x + threadIdx.x;
    if (idx >= BATCH*NOBJ*GHID) return;
    int b = idx / (NOBJ*GHID);
    int rem = idx - b*(NOBJ*GHID);
    int o = rem / GHID, n = rem % GHID;
    const float* wj = g1w + n*548 + 500;
    const float* wi = g1w + n*548 + 524;
    float si = 0.f, sj = 0.f;
    #pragma unroll
    for (int c = 0; c < 24; ++c){
        float v = conv[((size_t)b*24 + c)*NOBJ + o];
        sj += v*wj[c];
        si += v*wi[c];
    }
    ip[idx] = si;
    jp[idx] = sj;
}

// ---------------- MFMA pair kernel ----------------
// grid 256 = b(64) x ic(4).  Per block: pairs (i = ic*16+il, all 64 j), M=1024, N=112, K=128.
// A = relu(qp+ip_i+jp_j) built in registers from padded LDS; B = g2w f16 LDS.
// Epilogue: relu(acc + g2b) accumulated per-lane, wave/block reduce -> part[b*4+ic][100].
__global__ __launch_bounds__(256, 1) void k_pair_mfma(
    const float* __restrict__ qp, const float* __restrict__ ip,
    const float* __restrict__ jp, const float* __restrict__ g2w,
    const float* __restrict__ g2b, float* __restrict__ part)
{
    __shared__ float    jpl[NOBJ][132];     // 33792 B (stride 132: 2-way banks)
    __shared__ float    basel[16][132];     //  8448 B
    __shared__ _Float16 g2h[112][136];      // 30464 B (stride 136 f16)
    __shared__ float    redx[4][112];       //  1792 B

    int b  = blockIdx.x >> 2;
    int ic = blockIdx.x & 3;
    int tid = threadIdx.x;
    int w = tid >> 6, lane = tid & 63;
    int ncol = lane & 15, kb = lane >> 4;

    // stage jp (64x100) + zero pad
    for (int i = tid; i < NOBJ*100; i += 256){
        int j = i / 100, k = i - (i/100)*100;
        jpl[j][k] = jp[((size_t)b*NOBJ + j)*GHID + k];
    }
    for (int i = tid; i < NOBJ*32; i += 256)
        jpl[i >> 5][100 + (i & 31)] = 0.f;
    // stage base = qp + ip_i (16x100) + zero pad
    for (int i = tid; i < 16*100; i += 256){
        int il = i / 100, k = i - (i/100)*100;
        basel[il][k] = qp[b*GHID + k] + ip[((size_t)b*NOBJ + ic*16 + il)*GHID + k];
    }
    for (int i = tid; i < 16*32; i += 256)
        basel[i >> 5][100 + (i & 31)] = 0.f;
    // stage g2w -> f16, padded
    for (int i = tid; i < 112*136; i += 256){
        int n = i / 136, k = i - (i/136)*136;
        g2h[n][k] = (n < 100 && k < 100) ? (_Float16)g2w[n*GHID + k] : (_Float16)0.f;
    }
    // g2b into registers (pad -> 0; pad cols have zero B rows so relu(0+0)=0)
    float gb7[7];
    #pragma unroll
    for (int nt = 0; nt < 7; ++nt){
        int n = nt*16 + ncol;
        gb7[nt] = (n < 100) ? g2b[n] : 0.f;
    }
    __syncthreads();

    f32x4 sacc[7] = {};
    // wave w: il = w*4..w*4+3; jc = 0..3
    #pragma unroll
    for (int it = 0; it < 4; ++it){
        int il = w*4 + it;
        #pragma unroll
        for (int jc = 0; jc < 4; ++jc){
            f32x4 acc[7] = {};
            int jrow = jc*16 + ncol;
            #pragma unroll
            for (int ks = 0; ks < 4; ++ks){
                int k0 = ks*32 + kb*8;
                const float* jpp = &jpl[jrow][k0];
                const float* bpp = &basel[il][k0];
                half8 af;
                #pragma unroll
                for (int e = 0; e < 8; ++e)
                    af[e] = (_Float16)fmaxf(jpp[e] + bpp[e], 0.f);
                #pragma unroll
                for (int nt = 0; nt < 7; ++nt){
                    half8 bf = *(const half8*)&g2h[nt*16 + ncol][k0];
                    acc[nt] = __builtin_amdgcn_mfma_f32_16x16x32_f16(af, bf, acc[nt], 0, 0, 0);
                }
            }
            // h2 = relu(P + g2b), accumulate
            #pragma unroll
            for (int nt = 0; nt < 7; ++nt)
                #pragma unroll
                for (int r = 0; r < 4; ++r)
                    sacc[nt][r] += fmaxf(acc[nt][r] + gb7[nt], 0.f);
        }
    }
    // reduce: rows within lane, then kb groups across lanes, then waves via LDS
    #pragma unroll
    for (int nt = 0; nt < 7; ++nt){
        float s = sacc[nt][0] + sacc[nt][1] + sacc[nt][2] + sacc[nt][3];
        s += __shfl_xor(s, 16);
        s += __shfl_xor(s, 32);
        if (lane < 16) redx[w][nt*16 + lane] = s;
    }
    __syncthreads();
    if (tid < 100){
        float p = redx[0][tid] + redx[1][tid] + redx[2][tid] + redx[3][tid];
        part[(size_t)(b*4 + ic)*GHID + tid] = p;
    }
}

// ---------------- final: reduce partials, f1, f2, log_softmax ----------------
__global__ __launch_bounds__(256) void k_final(const float* __restrict__ part, const float* __restrict__ f1w,
               const float* __restrict__ f1b, const float* __restrict__ f2w,
               const float* __restrict__ f2b, float* __restrict__ out)
{
    int b = blockIdx.x;
    int tid = threadIdx.x;
    __shared__ float gs[GHID];
    __shared__ float fh[GHID];
    __shared__ float lg[ANSN];
    __shared__ float red[4], red2[4];
    if (tid < GHID){
        float s = 0.f;
        for (int ic = 0; ic < 4; ++ic) s += part[((size_t)b*4 + ic)*GHID + tid];
        gs[tid] = s;
    }
    __syncthreads();
    if (tid < GHID){
        float s = f1b[tid];
        const float* w = f1w + tid*GHID;
        for (int k = 0; k < GHID; ++k) s += gs[k]*w[k];
        fh[tid] = fmaxf(s, 0.f);
    }
    __syncthreads();
    for (int n = tid; n < ANSN; n += 256){
        float s = f2b[n];
        const float* w = f2w + (size_t)n*GHID;
        for (int k = 0; k < GHID; ++k) s += fh[k]*w[k];
        lg[n] = fmaxf(s, 0.f);
    }
    __syncthreads();
    float mx = -1e30f;
    for (int n = tid; n < ANSN; n += 256) mx = fmaxf(mx, lg[n]);
    #pragma unroll
    for (int off = 32; off > 0; off >>= 1) mx = fmaxf(mx, __shfl_xor(mx, off));
    if ((tid & 63) == 0) red[tid >> 6] = mx;
    __syncthreads();
    mx = fmaxf(fmaxf(red[0], red[1]), fmaxf(red[2], red[3]));
    float se = 0.f;
    for (int n = tid; n < ANSN; n += 256) se += expf(lg[n]-mx);
    #pragma unroll
    for (int off = 32; off > 0; off >>= 1) se += __shfl_xor(se, off);
    if ((tid & 63) == 0) red2[tid >> 6] = se;
    __syncthreads();
    se = red2[0]+red2[1]+red2[2]+red2[3];
    float lse = logf(se);
    for (int n = tid; n < ANSN; n += 256) out[(size_t)b*ANSN + n] = lg[n] - mx - lse;
}

extern "C" void kernel_launch(void* const* d_in, const int* in_sizes, int n_in,
                              void* d_out, int out_size, void* d_ws, size_t ws_size,
                              hipStream_t stream)
{
    const int*   sent  = (const int*)  d_in[0];
    const float* conv  = (const float*)d_in[1];
    const int*   lens  = (const int*)  d_in[2];
    const float* table = (const float*)d_in[3];
    const float* W_ih  = (const float*)d_in[4];
    const float* W_hh  = (const float*)d_in[5];
    const float* b_ih  = (const float*)d_in[6];
    const float* b_hh  = (const float*)d_in[7];
    const float* h0    = (const float*)d_in[8];
    const float* c0    = (const float*)d_in[9];
    const float* g1_w  = (const float*)d_in[10];
    const float* g1_b  = (const float*)d_in[11];
    const float* g2_w  = (const float*)d_in[12];
    const float* g2_b  = (const float*)d_in[13];
    const float* f1_w  = (const float*)d_in[14];
    const float* f1_b  = (const float*)d_in[15];
    const float* f2_w  = (const float*)d_in[16];
    const float* f2_b  = (const float*)d_in[17];
    float* out = (float*)d_out;

    float* ws   = (float*)d_ws;
    int*   slots= (int*)d_ws;                          // 100 slots * 32 ints
    _Float16* hF = (_Float16*)(ws + 16384);            // 2*4*16*512 f16 = 128 KB
    float* hqT  = ws + 16384 + 32768;                  // 500*64
    float* embT = hqT + HIDD*64;                       // 300*2048
    float* xgT  = embT + (size_t)EMBD*MCOL;            // 2000*2048
    float* qp   = xgT  + (size_t)4*HIDD*MCOL;          // 64*100
    float* ip   = qp   + BATCH*GHID;                   // 64*64*100
    float* jp   = ip   + BATCH*NOBJ*GHID;
    float* part = jp   + BATCH*NOBJ*GHID;              // 256*100

    // 0. zero barrier region (deterministic across graph replays)
    hipMemsetAsync(slots, 0, 16384*sizeof(float), stream);

    // 1. embedding gather, transposed
    {
        dim3 g(3, SEQL);
        k_embT<<<g, 256, 0, stream>>>(sent, table, embT);
    }

    // 2. xgT = W_ih @ embT + (b_ih+b_hh)
    {
        dim3 g(MCOL/64, (4*HIDD + 63)/64);
        k_gemm_nn<<<g, 256, 0, stream>>>(W_ih, embT, b_ih, b_hh, xgT,
                                         4*HIDD, MCOL, EMBD);
    }

    // 3. MFMA LSTM, 100 blocks (4 groups x 25), group-local one-hop barriers
    {
        _Float16* hF_p = hF; float* hqT_p = hqT;
        const float* xgT_p = xgT; const float* Whh_p = W_hh;
        const float* h0_p = h0; const float* c0_p = c0; const int* lens_p = lens;
        int* slots_p = slots;
        void* kargs[] = { (void*)&hF_p, (void*)&hqT_p, (void*)&xgT_p, (void*)&Whh_p,
                          (void*)&h0_p, (void*)&c0_p, (void*)&lens_p, (void*)&slots_p };
        hipLaunchCooperativeKernel((const void*)k_lstm_v8, dim3(NBLK), dim3(320),
                                   kargs, 0, stream);
    }

    // 4. g_mlp layer-1 partials
    k_qp<<<(BATCH*GHID + 255)/256, 256, 0, stream>>>(hqT, g1_w, g1_b, qp);
    k_ipjp<<<(BATCH*NOBJ*GHID + 255)/256, 256, 0, stream>>>(conv, g1_w, ip, jp);

    // 5. MFMA pair kernel -> part[256][100]
    k_pair_mfma<<<BATCH*4, 256, 0, stream>>>(qp, ip, jp, g2_w, g2_b, part);

    // 6. final MLP + log_softmax
    k_final<<<BATCH, 256, 0, stream>>>(part, f1_w, f1_b, f2_w, f2_b, out);
}